// Round 6
// baseline (17267.093 us; speedup 1.0000x reference)
//
#include <hip/hip_runtime.h>

#define LEAKY(v) ((v) >= 0.f ? (v) : 0.01f * (v))

// ---------------- Layer 1 (CIN=3, PH=1, dual tower) ----------------
// grid (1, 15, 32), block 256. blockIdx.z = z*16 + cout_group(4 couts).
__global__ void conv3(const float* __restrict__ in, int inRow0,
                      const float* __restrict__ w0, const float* __restrict__ b0,
                      const float* __restrict__ w1, const float* __restrict__ b1,
                      float* __restrict__ out, int outZS)
{
    const int wcol = threadIdx.x;
    const int h  = blockIdx.y;        // 0..14
    const int cg = blockIdx.z & 15;
    const int z  = blockIdx.z >> 4;
    const float* W  = (z ? w1 : w0) + cg * 4 * 27;
    const float* Bv = z ? b1 : b0;

    float acc[4];
    #pragma unroll
    for (int j = 0; j < 4; ++j) acc[j] = Bv[cg * 4 + j];

    #pragma unroll
    for (int kh = 0; kh < 3; ++kh) {
        const int r = h - 1 + kh;
        const bool valid = (r >= 0 && r < 15);          // slice zero-pad
        const float msk = valid ? 1.f : 0.f;
        const float* rr = in + (inRow0 + (valid ? r : 0)) * 256;
        #pragma unroll
        for (int c = 0; c < 3; ++c) {
            const float* rc = rr + c * 31 * 256;        // ebuf channel stride
            float vm = (wcol > 0)   ? rc[wcol - 1] : 0.f;
            float v0 = rc[wcol];
            float vp = (wcol < 255) ? rc[wcol + 1] : 0.f;
            vm *= msk; v0 *= msk; vp *= msk;
            #pragma unroll
            for (int j = 0; j < 4; ++j) {
                const float* wj = W + j * 27 + c * 9 + kh * 3;
                acc[j] += vm * wj[0] + v0 * wj[1] + vp * wj[2];
            }
        }
    }
    float* o = out + (size_t)z * outZS;
    #pragma unroll
    for (int j = 0; j < 4; ++j)
        o[(cg * 4 + j) * 15 * 256 + h * 256 + wcol] = LEAKY(acc[j]);
}

// ---------------- CIN=64, PH=0 conv, cin-split over threadIdx.y ----------------
// grid (1, HOUT, NZ*16), block (256,4). threadIdx.y owns 16 cins.
// 16 waves/block -> ~26 waves/CU at 416 blocks: TLP hides load latency.
template<int HOUT, int NZ>
__global__ __launch_bounds__(1024) void convY(
    const float* __restrict__ in, int inChS, int inZS,
    const float* __restrict__ w0, const float* __restrict__ b0,
    const float* __restrict__ w1, const float* __restrict__ b1,
    float* __restrict__ out, int outZS)
{
    const int x  = threadIdx.x;         // output column
    const int y  = threadIdx.y;         // cin slice (0..3)
    const int h  = blockIdx.y;          // output row
    const int cg = blockIdx.z & 15;     // cout group of 4
    const int z  = blockIdx.z >> 4;     // tower
    const float* W  = (z ? w1 : w0) + cg * 4 * 576;   // 64*9 per cout
    const float* Bv = z ? b1 : b0;
    const float* ib = in + (size_t)z * inZS + h * 256 + y * 16 * inChS;
    float* o = out + (size_t)z * outZS;

    const bool mL = (x > 0), mR = (x < 255);

    float acc[4] = {0.f, 0.f, 0.f, 0.f};

    #pragma unroll 4
    for (int c = 0; c < 16; ++c) {
        const float* r_ = ib + c * inChS;
        float v[9];
        #pragma unroll
        for (int kh = 0; kh < 3; ++kh) {
            const float* rr = r_ + kh * 256;
            v[kh * 3 + 0] = mL ? rr[x - 1] : 0.f;
            v[kh * 3 + 1] = rr[x];
            v[kh * 3 + 2] = mR ? rr[x + 1] : 0.f;
        }
        const int cin = y * 16 + c;
        #pragma unroll
        for (int j = 0; j < 4; ++j) {
            const float* wj = W + j * 576 + cin * 9;
            #pragma unroll
            for (int t = 0; t < 9; ++t) acc[j] += v[t] * wj[t];
        }
    }

    __shared__ float red[4][4][256];    // [slice][cout_j][col] = 16 KB
    #pragma unroll
    for (int j = 0; j < 4; ++j) red[y][j][x] = acc[j];
    __syncthreads();

    // thread (x,y) finalizes cout cg*4+y
    float v = Bv[cg * 4 + y] + red[0][y][x] + red[1][y][x] + red[2][y][x] + red[3][y][x];
    o[(cg * 4 + y) * HOUT * 256 + h * 256 + x] = LEAKY(v);
}

// ---------------- Per-pixel 8x8 @ 8x8 ----------------
// grid (9, 8), block 256. blockIdx.y = i (output row-of-8). Thread = pixel.
__global__ void mm88(const float* __restrict__ tw, float* __restrict__ p0)
{
    const int idx = blockIdx.x * 256 + threadIdx.x;   // pixel in 9*256
    const int i   = blockIdx.y;                       // 0..7
    const float* s = tw;
    const float* e = tw + 64 * 9 * 256;
    float sv[64];
    #pragma unroll
    for (int c = 0; c < 64; ++c) sv[c] = s[c * 9 * 256 + idx];
    float ev[8];
    #pragma unroll
    for (int j = 0; j < 8; ++j) ev[j] = e[(i * 8 + j) * 9 * 256 + idx];
    #pragma unroll
    for (int k = 0; k < 8; ++k) {
        float acc = 0.f;
        #pragma unroll
        for (int j = 0; j < 8; ++j) acc += ev[j] * sv[j * 8 + k];
        p0[(i * 8 + k) * 9 * 256 + idx] = acc;
    }
}

// ---------------- conv9 (64->3, kh=1 taps only) + recurrence update ----------------
// block (256,4): threadIdx.y owns 16 cins, unroll-bounded; LDS reduce.
__global__ void conv9up(const float* __restrict__ pin, const float* __restrict__ w9,
                        const float* __restrict__ b9, const float* __restrict__ x,
                        float* __restrict__ ebuf, float* __restrict__ preds, int i)
{
    const int wcol = threadIdx.x;
    const int yq   = threadIdx.y;       // 0..3
    const int c0   = yq * 16;
    const bool mL = (wcol > 0), mR = (wcol < 255);
    float a0 = 0.f, a1 = 0.f, a2 = 0.f;

    #pragma unroll 4
    for (int c = 0; c < 16; ++c) {
        const int cin = c0 + c;
        const float* r_ = pin + cin * 256;
        float vm = mL ? r_[wcol - 1] : 0.f;
        float v0 = r_[wcol];
        float vp = mR ? r_[wcol + 1] : 0.f;
        const float* wk0 = w9 + (0 * 64 + cin) * 9 + 3;   // kh=1
        const float* wk1 = w9 + (1 * 64 + cin) * 9 + 3;
        const float* wk2 = w9 + (2 * 64 + cin) * 9 + 3;
        a0 += vm * wk0[0] + v0 * wk0[1] + vp * wk0[2];
        a1 += vm * wk1[0] + v0 * wk1[1] + vp * wk1[2];
        a2 += vm * wk2[0] + v0 * wk2[1] + vp * wk2[2];
    }

    __shared__ float red[4][3][256];
    red[yq][0][wcol] = a0;
    red[yq][1][wcol] = a1;
    red[yq][2][wcol] = a2;
    __syncthreads();

    if (yq == 0) {
        #pragma unroll
        for (int j = 0; j < 3; ++j) {
            float v = b9[j] + red[0][j][wcol] + red[1][j][wcol]
                            + red[2][j][wcol] + red[3][j][wcol];
            v = LEAKY(v);
            preds[i * 768 + j * 256 + wcol] = v;
            ebuf[j * 31 * 256 + (15 + i) * 256 + wcol] =
                x[j * 31 * 256 + (15 + i) * 256 + wcol] - v;
        }
    }
}

// ---------------- finalize ----------------
__global__ void finalize(const float* __restrict__ preds, const float* __restrict__ ebuf,
                         float* __restrict__ o)
{
    const int idx = blockIdx.x * 256 + threadIdx.x;
    if (idx >= 24576) return;
    if (idx < 12288) {
        const int c = idx >> 12;
        const int t = (idx >> 8) & 15;
        const int w = idx & 255;
        o[idx] = preds[t * 768 + c * 256 + w];
    } else {
        const int j = idx - 12288;
        const int c = j >> 12;
        const int t = (j >> 8) & 15;
        const int w = j & 255;
        o[idx] = ebuf[c * 31 * 256 + (15 + t) * 256 + w];
    }
}

extern "C" void kernel_launch(void* const* d_in, const int* in_sizes, int n_in,
                              void* d_out, int out_size, void* d_ws, size_t ws_size,
                              hipStream_t stream)
{
    const float* x   = (const float*)d_in[0];
    const float* w1x = (const float*)d_in[1];  const float* b1x = (const float*)d_in[2];
    const float* w2x = (const float*)d_in[3];  const float* b2x = (const float*)d_in[4];
    const float* w3x = (const float*)d_in[5];  const float* b3x = (const float*)d_in[6];
    const float* w4x = (const float*)d_in[7];  const float* b4x = (const float*)d_in[8];
    const float* w1e = (const float*)d_in[9];  const float* b1e = (const float*)d_in[10];
    const float* w2e = (const float*)d_in[11]; const float* b2e = (const float*)d_in[12];
    const float* w3e = (const float*)d_in[13]; const float* b3e = (const float*)d_in[14];
    const float* w4e = (const float*)d_in[15]; const float* b4e = (const float*)d_in[16];
    const float* w5  = (const float*)d_in[17]; const float* b5  = (const float*)d_in[18];
    const float* w6  = (const float*)d_in[19]; const float* b6  = (const float*)d_in[20];
    const float* w7  = (const float*)d_in[21]; const float* b7  = (const float*)d_in[22];
    const float* w8  = (const float*)d_in[23]; const float* b8  = (const float*)d_in[24];
    const float* w9  = (const float*)d_in[25]; const float* b9  = (const float*)d_in[26];

    float* ws    = (float*)d_ws;
    float* ebuf  = ws;                   // 3*31*256    = 23808
    float* tA    = ebuf + 23808;         // 2*64*15*256 = 491520
    float* tB    = tA + 491520;          // 2*64*15*256 = 491520
    float* p0    = tB + 491520;          // 64*9*256    = 147456
    float* p1    = p0 + 147456;          // 64*9*256    = 147456
    float* preds = p1 + 147456;          // 16*3*256    = 12288

    hipMemcpyAsync(ebuf, x, 23808 * sizeof(float), hipMemcpyDeviceToDevice, stream);

    const dim3 blk(256, 4);
    for (int i = 0; i < 16; ++i) {
        conv3<<<dim3(1, 15, 32), 256, 0, stream>>>(ebuf, i, w1x, b1x, w1e, b1e,
                                                   tA, 64 * 15 * 256);
        convY<13, 2><<<dim3(1, 13, 32), blk, 0, stream>>>(tA, 15 * 256, 64 * 15 * 256,
                                                          w2x, b2x, w2e, b2e,
                                                          tB, 64 * 13 * 256);
        convY<11, 2><<<dim3(1, 11, 32), blk, 0, stream>>>(tB, 13 * 256, 64 * 13 * 256,
                                                          w3x, b3x, w3e, b3e,
                                                          tA, 64 * 11 * 256);
        convY<9, 2><<<dim3(1, 9, 32), blk, 0, stream>>>(tA, 11 * 256, 64 * 11 * 256,
                                                        w4x, b4x, w4e, b4e,
                                                        tB, 64 * 9 * 256);
        mm88<<<dim3(9, 8), 256, 0, stream>>>(tB, p0);
        convY<7, 1><<<dim3(1, 7, 16), blk, 0, stream>>>(p0, 9 * 256, 0,
                                                        w5, b5, w5, b5, p1, 0);
        convY<5, 1><<<dim3(1, 5, 16), blk, 0, stream>>>(p1, 7 * 256, 0,
                                                        w6, b6, w6, b6, p0, 0);
        convY<3, 1><<<dim3(1, 3, 16), blk, 0, stream>>>(p0, 5 * 256, 0,
                                                        w7, b7, w7, b7, p1, 0);
        convY<1, 1><<<dim3(1, 1, 16), blk, 0, stream>>>(p1, 3 * 256, 0,
                                                        w8, b8, w8, b8, p0, 0);
        conv9up<<<dim3(1, 1, 1), dim3(256, 4), 0, stream>>>(p0, w9, b9, x, ebuf, preds, i);
    }

    finalize<<<96, 256, 0, stream>>>(preds, ebuf, (float*)d_out);
}

// Round 7
// 2591.994 us; speedup vs baseline: 6.6617x; 6.6617x over previous
//
#include <hip/hip_runtime.h>

#define LEAKY(v) ((v) >= 0.f ? (v) : 0.01f * (v))

// ---------------- Layer 1 (CIN=3, PH=1, dual tower) ----------------
// grid (1, 15, 32), block 256. blockIdx.z = z*16 + cout_group(4 couts).
__global__ void conv3(const float* __restrict__ in, int inRow0,
                      const float* __restrict__ w0, const float* __restrict__ b0,
                      const float* __restrict__ w1, const float* __restrict__ b1,
                      float* __restrict__ out, int outZS)
{
    const int wcol = threadIdx.x;
    const int h  = blockIdx.y;        // 0..14
    const int cg = blockIdx.z & 15;
    const int z  = blockIdx.z >> 4;
    const float* W  = (z ? w1 : w0) + cg * 4 * 27;
    const float* Bv = z ? b1 : b0;

    float acc[4];
    #pragma unroll
    for (int j = 0; j < 4; ++j) acc[j] = Bv[cg * 4 + j];

    #pragma unroll
    for (int kh = 0; kh < 3; ++kh) {
        const int r = h - 1 + kh;
        const bool valid = (r >= 0 && r < 15);          // slice zero-pad
        const float msk = valid ? 1.f : 0.f;
        const float* rr = in + (inRow0 + (valid ? r : 0)) * 256;
        #pragma unroll
        for (int c = 0; c < 3; ++c) {
            const float* rc = rr + c * 31 * 256;        // ebuf channel stride
            float vm = (wcol > 0)   ? rc[wcol - 1] : 0.f;
            float v0 = rc[wcol];
            float vp = (wcol < 255) ? rc[wcol + 1] : 0.f;
            vm *= msk; v0 *= msk; vp *= msk;
            #pragma unroll
            for (int j = 0; j < 4; ++j) {
                const float* wj = W + j * 27 + c * 9 + kh * 3;
                acc[j] += vm * wj[0] + v0 * wj[1] + vp * wj[2];
            }
        }
    }
    float* o = out + (size_t)z * outZS;
    #pragma unroll
    for (int j = 0; j < 4; ++j)
        o[(cg * 4 + j) * 15 * 256 + h * 256 + wcol] = LEAKY(acc[j]);
}

// ---------------- CIN=64, PH=0 conv: 256-thr block, unroll-4 pipeline ----------------
// grid (1, HOUT, NZ * 64/NCO), block 256. Thread: 1 col, NCO couts, 1 row.
// launch_bounds(256,2): VGPR cap 128 -> room for 36 in-flight loads, no spill.
// INCHS compile-time so load addresses fold to base+immediate.
template<int HOUT, int INCHS, int NCO>
__global__ __launch_bounds__(256, 2) void convU(
    const float* __restrict__ in, int inZS,
    const float* __restrict__ w0, const float* __restrict__ b0,
    const float* __restrict__ w1, const float* __restrict__ b1,
    float* __restrict__ out, int outZS)
{
    constexpr int NCG = 64 / NCO;
    const int x  = threadIdx.x;
    const int h  = blockIdx.y;
    const int cg = blockIdx.z % NCG;
    const int z  = blockIdx.z / NCG;
    const float* W  = (z ? w1 : w0) + cg * NCO * 576;   // 64*9 per cout
    const float* Bv = z ? b1 : b0;
    const float* ib = in + (size_t)z * inZS + h * 256;
    float* o = out + (size_t)z * outZS;

    const bool mL = (x > 0), mR = (x < 255);

    float acc[NCO];
    #pragma unroll
    for (int j = 0; j < NCO; ++j) acc[j] = Bv[cg * NCO + j];

    #pragma unroll 4
    for (int cin = 0; cin < 64; ++cin) {
        const float* r_ = ib + cin * INCHS;
        float v[9];
        #pragma unroll
        for (int kh = 0; kh < 3; ++kh) {
            const float* rr = r_ + kh * 256;
            v[kh * 3 + 0] = mL ? rr[x - 1] : 0.f;
            v[kh * 3 + 1] = rr[x];
            v[kh * 3 + 2] = mR ? rr[x + 1] : 0.f;
        }
        #pragma unroll
        for (int j = 0; j < NCO; ++j) {
            const float* wj = W + j * 576 + cin * 9;
            #pragma unroll
            for (int t = 0; t < 9; ++t) acc[j] += v[t] * wj[t];
        }
    }

    const int ohw = HOUT * 256;
    #pragma unroll
    for (int j = 0; j < NCO; ++j)
        o[(cg * NCO + j) * ohw + h * 256 + x] = LEAKY(acc[j]);
}

// ---------------- Per-pixel 8x8 @ 8x8 ----------------
// grid (9, 8), block 256. blockIdx.y = i (output row-of-8). Thread = pixel.
__global__ __launch_bounds__(256, 2) void mm88(const float* __restrict__ tw,
                                               float* __restrict__ p0)
{
    const int idx = blockIdx.x * 256 + threadIdx.x;   // pixel in 9*256
    const int i   = blockIdx.y;                       // 0..7
    const float* s = tw;
    const float* e = tw + 64 * 9 * 256;
    float sv[64];
    #pragma unroll
    for (int c = 0; c < 64; ++c) sv[c] = s[c * 9 * 256 + idx];
    float ev[8];
    #pragma unroll
    for (int j = 0; j < 8; ++j) ev[j] = e[(i * 8 + j) * 9 * 256 + idx];
    #pragma unroll
    for (int k = 0; k < 8; ++k) {
        float acc = 0.f;
        #pragma unroll
        for (int j = 0; j < 8; ++j) acc += ev[j] * sv[j * 8 + k];
        p0[(i * 8 + k) * 9 * 256 + idx] = acc;
    }
}

// ---------------- conv9 (64->3, kh=1 taps only) + recurrence update ----------------
// block (256,4): threadIdx.y owns 16 cins; LDS reduce; y==0 finalizes.
__global__ void conv9up(const float* __restrict__ pin, const float* __restrict__ w9,
                        const float* __restrict__ b9, const float* __restrict__ x,
                        float* __restrict__ ebuf, float* __restrict__ preds, int i)
{
    const int wcol = threadIdx.x;
    const int yq   = threadIdx.y;       // 0..3
    const int c0   = yq * 16;
    const bool mL = (wcol > 0), mR = (wcol < 255);
    float a0 = 0.f, a1 = 0.f, a2 = 0.f;

    #pragma unroll 4
    for (int c = 0; c < 16; ++c) {
        const int cin = c0 + c;
        const float* r_ = pin + cin * 256;
        float vm = mL ? r_[wcol - 1] : 0.f;
        float v0 = r_[wcol];
        float vp = mR ? r_[wcol + 1] : 0.f;
        const float* wk0 = w9 + (0 * 64 + cin) * 9 + 3;   // kh=1
        const float* wk1 = w9 + (1 * 64 + cin) * 9 + 3;
        const float* wk2 = w9 + (2 * 64 + cin) * 9 + 3;
        a0 += vm * wk0[0] + v0 * wk0[1] + vp * wk0[2];
        a1 += vm * wk1[0] + v0 * wk1[1] + vp * wk1[2];
        a2 += vm * wk2[0] + v0 * wk2[1] + vp * wk2[2];
    }

    __shared__ float red[4][3][256];
    red[yq][0][wcol] = a0;
    red[yq][1][wcol] = a1;
    red[yq][2][wcol] = a2;
    __syncthreads();

    if (yq == 0) {
        #pragma unroll
        for (int j = 0; j < 3; ++j) {
            float v = b9[j] + red[0][j][wcol] + red[1][j][wcol]
                            + red[2][j][wcol] + red[3][j][wcol];
            v = LEAKY(v);
            preds[i * 768 + j * 256 + wcol] = v;
            ebuf[j * 31 * 256 + (15 + i) * 256 + wcol] =
                x[j * 31 * 256 + (15 + i) * 256 + wcol] - v;
        }
    }
}

// ---------------- finalize ----------------
__global__ void finalize(const float* __restrict__ preds, const float* __restrict__ ebuf,
                         float* __restrict__ o)
{
    const int idx = blockIdx.x * 256 + threadIdx.x;
    if (idx >= 24576) return;
    if (idx < 12288) {
        const int c = idx >> 12;
        const int t = (idx >> 8) & 15;
        const int w = idx & 255;
        o[idx] = preds[t * 768 + c * 256 + w];
    } else {
        const int j = idx - 12288;
        const int c = j >> 12;
        const int t = (j >> 8) & 15;
        const int w = j & 255;
        o[idx] = ebuf[c * 31 * 256 + (15 + t) * 256 + w];
    }
}

extern "C" void kernel_launch(void* const* d_in, const int* in_sizes, int n_in,
                              void* d_out, int out_size, void* d_ws, size_t ws_size,
                              hipStream_t stream)
{
    const float* x   = (const float*)d_in[0];
    const float* w1x = (const float*)d_in[1];  const float* b1x = (const float*)d_in[2];
    const float* w2x = (const float*)d_in[3];  const float* b2x = (const float*)d_in[4];
    const float* w3x = (const float*)d_in[5];  const float* b3x = (const float*)d_in[6];
    const float* w4x = (const float*)d_in[7];  const float* b4x = (const float*)d_in[8];
    const float* w1e = (const float*)d_in[9];  const float* b1e = (const float*)d_in[10];
    const float* w2e = (const float*)d_in[11]; const float* b2e = (const float*)d_in[12];
    const float* w3e = (const float*)d_in[13]; const float* b3e = (const float*)d_in[14];
    const float* w4e = (const float*)d_in[15]; const float* b4e = (const float*)d_in[16];
    const float* w5  = (const float*)d_in[17]; const float* b5  = (const float*)d_in[18];
    const float* w6  = (const float*)d_in[19]; const float* b6  = (const float*)d_in[20];
    const float* w7  = (const float*)d_in[21]; const float* b7  = (const float*)d_in[22];
    const float* w8  = (const float*)d_in[23]; const float* b8  = (const float*)d_in[24];
    const float* w9  = (const float*)d_in[25]; const float* b9  = (const float*)d_in[26];

    float* ws    = (float*)d_ws;
    float* ebuf  = ws;                   // 3*31*256    = 23808
    float* tA    = ebuf + 23808;         // 2*64*15*256 = 491520
    float* tB    = tA + 491520;          // 2*64*15*256 = 491520
    float* p0    = tB + 491520;          // 64*9*256    = 147456
    float* p1    = p0 + 147456;          // 64*9*256    = 147456
    float* preds = p1 + 147456;          // 16*3*256    = 12288

    hipMemcpyAsync(ebuf, x, 23808 * sizeof(float), hipMemcpyDeviceToDevice, stream);

    for (int i = 0; i < 16; ++i) {
        conv3<<<dim3(1, 15, 32), 256, 0, stream>>>(ebuf, i, w1x, b1x, w1e, b1e,
                                                   tA, 64 * 15 * 256);
        convU<13, 15 * 256, 2><<<dim3(1, 13, 64), 256, 0, stream>>>(
            tA, 64 * 15 * 256, w2x, b2x, w2e, b2e, tB, 64 * 13 * 256);
        convU<11, 13 * 256, 2><<<dim3(1, 11, 64), 256, 0, stream>>>(
            tB, 64 * 13 * 256, w3x, b3x, w3e, b3e, tA, 64 * 11 * 256);
        convU<9, 11 * 256, 2><<<dim3(1, 9, 64), 256, 0, stream>>>(
            tA, 64 * 11 * 256, w4x, b4x, w4e, b4e, tB, 64 * 9 * 256);
        mm88<<<dim3(9, 8), 256, 0, stream>>>(tB, p0);
        convU<7, 9 * 256, 2><<<dim3(1, 7, 32), 256, 0, stream>>>(
            p0, 0, w5, b5, w5, b5, p1, 0);
        convU<5, 7 * 256, 2><<<dim3(1, 5, 32), 256, 0, stream>>>(
            p1, 0, w6, b6, w6, b6, p0, 0);
        convU<3, 5 * 256, 2><<<dim3(1, 3, 32), 256, 0, stream>>>(
            p0, 0, w7, b7, w7, b7, p1, 0);
        convU<1, 3 * 256, 2><<<dim3(1, 1, 32), 256, 0, stream>>>(
            p1, 0, w8, b8, w8, b8, p0, 0);
        conv9up<<<dim3(1, 1, 1), dim3(256, 4), 0, stream>>>(p0, w9, b9, x, ebuf, preds, i);
    }

    finalize<<<96, 256, 0, stream>>>(preds, ebuf, (float*)d_out);
}

// Round 11
// 2537.344 us; speedup vs baseline: 6.8052x; 1.0215x over previous
//
#include <hip/hip_runtime.h>

#define LEAKY(v) ((v) >= 0.f ? (v) : 0.01f * (v))

// ---------------- L1: CIN=3, PH=1 (slice-local), dual tower, quad-col ----------------
// grid (1, 15, 8): z=bz>>2, cq=bz&3. block 256 = 4 waves; wave wv -> couts cq*16+wv*4 ..+3.
// Each lane owns cols 4*lane..4*lane+3 of the full 256-wide row.
__global__ __launch_bounds__(256, 2) void conv3Q(
    const float* __restrict__ ebuf, int i0,
    const float* __restrict__ w0, const float* __restrict__ b0,
    const float* __restrict__ w1, const float* __restrict__ b1,
    float* __restrict__ out)
{
    const int lane = threadIdx.x & 63;
    const int wv   = threadIdx.x >> 6;
    const int h  = blockIdx.y;             // 0..14
    const int cq = blockIdx.z & 3;
    const int z  = blockIdx.z >> 2;
    const int cout0 = __builtin_amdgcn_readfirstlane(cq * 16 + wv * 4);
    const float* W  = (z ? w1 : w0) + cout0 * 27;
    const float* Bv = z ? b1 : b0;

    float a[4][4] = {};
    #pragma unroll
    for (int kh = 0; kh < 3; ++kh) {
        const int r = h - 1 + kh;
        const bool valid = (r >= 0 && r < 15);          // pad within 15-row slice
        const float msk = valid ? 1.f : 0.f;
        #pragma unroll
        for (int c = 0; c < 3; ++c) {
            const float* rr = ebuf + c * (31 * 256) + (i0 + (valid ? r : 0)) * 256 + lane * 4;
            float4 v = *(const float4*)rr;
            v.x *= msk; v.y *= msk; v.z *= msk; v.w *= msk;
            float wl = __shfl_up(v.w, 1);   if (lane == 0)  wl = 0.f;
            float wr = __shfl_down(v.x, 1); if (lane == 63) wr = 0.f;
            const float win[6] = {wl, v.x, v.y, v.z, v.w, wr};
            #pragma unroll
            for (int j = 0; j < 4; ++j) {
                const float* wj = W + j * 27 + c * 9 + kh * 3;
                #pragma unroll
                for (int cc = 0; cc < 4; ++cc)
                    a[j][cc] += wj[0] * win[cc] + wj[1] * win[cc + 1] + wj[2] * win[cc + 2];
            }
        }
    }
    float* o = out + (size_t)z * 245760 + h * 256 + lane * 4;
    #pragma unroll
    for (int j = 0; j < 4; ++j) {
        const float bb = Bv[cout0 + j];
        float4 r4;
        r4.x = LEAKY(a[j][0] + bb);
        r4.y = LEAKY(a[j][1] + bb);
        r4.z = LEAKY(a[j][2] + bb);
        r4.w = LEAKY(a[j][3] + bb);
        *(float4*)(o + (cout0 + j) * (15 * 256)) = r4;
    }
}

// ---------------- CIN=64, PH=0 conv: quad-col + shuffle, NCO=1 ----------------
// grid (1, HOUT, NZ*16): block 256 = 4 waves; wave -> one cout; lane -> 4 cols.
// Input rows h..h+2 always valid (INH = HOUT + 2). Tower strides 64*INH*256 / 64*HOUT*256.
template<int HOUT, int INH, int NZ>
__global__ __launch_bounds__(256, 2) void convQ(
    const float* __restrict__ in,
    const float* __restrict__ w0, const float* __restrict__ b0,
    const float* __restrict__ w1, const float* __restrict__ b1,
    float* __restrict__ out)
{
    const int lane = threadIdx.x & 63;
    const int wv   = threadIdx.x >> 6;
    const int h  = blockIdx.y;
    const int gz = blockIdx.z;                 // 0 .. NZ*16-1
    const int z  = (NZ == 2) ? (gz >> 4) : 0;
    const int cout = __builtin_amdgcn_readfirstlane((gz & 15) * 4 + wv);
    const float* W  = (z ? w1 : w0) + cout * 576;
    const float* Bv = z ? b1 : b0;
    const float* ib = in + (size_t)z * (64 * INH * 256) + h * 256 + lane * 4;

    float acc[4] = {};

    #pragma unroll 4
    for (int cin = 0; cin < 64; ++cin) {
        const float* r_ = ib + cin * (INH * 256);
        #pragma unroll
        for (int kh = 0; kh < 3; ++kh) {
            float4 v = *(const float4*)(r_ + kh * 256);
            float wl = __shfl_up(v.w, 1);   if (lane == 0)  wl = 0.f;
            float wr = __shfl_down(v.x, 1); if (lane == 63) wr = 0.f;
            const float win[6] = {wl, v.x, v.y, v.z, v.w, wr};
            const float* wj = W + cin * 9 + kh * 3;
            #pragma unroll
            for (int c = 0; c < 4; ++c)
                acc[c] += wj[0] * win[c] + wj[1] * win[c + 1] + wj[2] * win[c + 2];
        }
    }

    const float bb = Bv[cout];
    float4 r4;
    r4.x = LEAKY(acc[0] + bb);
    r4.y = LEAKY(acc[1] + bb);
    r4.z = LEAKY(acc[2] + bb);
    r4.w = LEAKY(acc[3] + bb);
    float* o = out + (size_t)z * (64 * HOUT * 256) + cout * (HOUT * 256) + h * 256 + lane * 4;
    *(float4*)o = r4;
}

// ---------------- Per-pixel 8x8 @ 8x8 (fp32) ----------------
// grid (9, 8), block 256. blockIdx.y = i (output row-of-8). Thread = pixel.
// Input tB: two towers, 64 ch x 9 rows x 256 cols each -> tower stride 64*9*256.
__global__ __launch_bounds__(256, 2) void mm88(const float* __restrict__ tw,
                                               float* __restrict__ p0)
{
    const int idx = blockIdx.x * 256 + threadIdx.x;   // pixel in 9*256
    const int i   = blockIdx.y;                       // 0..7
    const float* s = tw;                              // tower 0 (x-weights / s)
    const float* e = tw + 64 * 9 * 256;               // tower 1 (e)  [BUG FIX: was +245760]
    float sv[64];
    #pragma unroll
    for (int c = 0; c < 64; ++c) sv[c] = s[c * (9 * 256) + idx];
    float ev[8];
    #pragma unroll
    for (int j = 0; j < 8; ++j) ev[j] = e[(i * 8 + j) * (9 * 256) + idx];
    #pragma unroll
    for (int k = 0; k < 8; ++k) {
        float acc = 0.f;
        #pragma unroll
        for (int j = 0; j < 8; ++j) acc += ev[j] * sv[j * 8 + k];
        p0[(i * 8 + k) * (9 * 256) + idx] = acc;
    }
}

// ---------------- conv9 (64->3, kh=1 taps only) + recurrence update ----------------
// block (256,4): threadIdx.y owns 16 cins; LDS reduce; y==0 finalizes.
__global__ void conv9up(const float* __restrict__ pin, const float* __restrict__ w9,
                        const float* __restrict__ b9, const float* __restrict__ x,
                        float* __restrict__ ebuf, float* __restrict__ preds, int i)
{
    const int wcol = threadIdx.x;
    const int yq   = threadIdx.y;       // 0..3
    const int c0   = yq * 16;
    const bool mL = (wcol > 0), mR = (wcol < 255);
    float a0 = 0.f, a1 = 0.f, a2 = 0.f;

    #pragma unroll 4
    for (int c = 0; c < 16; ++c) {
        const int cin = c0 + c;
        const float* r_ = pin + cin * 256;
        float vm = mL ? r_[wcol - 1] : 0.f;
        float v0 = r_[wcol];
        float vp = mR ? r_[wcol + 1] : 0.f;
        const float* wk0 = w9 + (0 * 64 + cin) * 9 + 3;   // kh=1
        const float* wk1 = w9 + (1 * 64 + cin) * 9 + 3;
        const float* wk2 = w9 + (2 * 64 + cin) * 9 + 3;
        a0 += vm * wk0[0] + v0 * wk0[1] + vp * wk0[2];
        a1 += vm * wk1[0] + v0 * wk1[1] + vp * wk1[2];
        a2 += vm * wk2[0] + v0 * wk2[1] + vp * wk2[2];
    }

    __shared__ float red[4][3][256];
    red[yq][0][wcol] = a0;
    red[yq][1][wcol] = a1;
    red[yq][2][wcol] = a2;
    __syncthreads();

    if (yq == 0) {
        #pragma unroll
        for (int j = 0; j < 3; ++j) {
            float v = b9[j] + red[0][j][wcol] + red[1][j][wcol]
                            + red[2][j][wcol] + red[3][j][wcol];
            v = LEAKY(v);
            preds[i * 768 + j * 256 + wcol] = v;
            ebuf[j * 31 * 256 + (15 + i) * 256 + wcol] =
                x[j * 31 * 256 + (15 + i) * 256 + wcol] - v;
        }
    }
}

// ---------------- finalize ----------------
__global__ void finalize(const float* __restrict__ preds, const float* __restrict__ ebuf,
                         float* __restrict__ o)
{
    const int idx = blockIdx.x * 256 + threadIdx.x;
    if (idx >= 24576) return;
    if (idx < 12288) {
        const int c = idx >> 12;
        const int t = (idx >> 8) & 15;
        const int w = idx & 255;
        o[idx] = preds[t * 768 + c * 256 + w];
    } else {
        const int j = idx - 12288;
        const int c = j >> 12;
        const int t = (j >> 8) & 15;
        const int w = j & 255;
        o[idx] = ebuf[c * 31 * 256 + (15 + t) * 256 + w];
    }
}

extern "C" void kernel_launch(void* const* d_in, const int* in_sizes, int n_in,
                              void* d_out, int out_size, void* d_ws, size_t ws_size,
                              hipStream_t stream)
{
    const float* x   = (const float*)d_in[0];
    const float* w1x = (const float*)d_in[1];  const float* b1x = (const float*)d_in[2];
    const float* w2x = (const float*)d_in[3];  const float* b2x = (const float*)d_in[4];
    const float* w3x = (const float*)d_in[5];  const float* b3x = (const float*)d_in[6];
    const float* w4x = (const float*)d_in[7];  const float* b4x = (const float*)d_in[8];
    const float* w1e = (const float*)d_in[9];  const float* b1e = (const float*)d_in[10];
    const float* w2e = (const float*)d_in[11]; const float* b2e = (const float*)d_in[12];
    const float* w3e = (const float*)d_in[13]; const float* b3e = (const float*)d_in[14];
    const float* w4e = (const float*)d_in[15]; const float* b4e = (const float*)d_in[16];
    const float* w5  = (const float*)d_in[17]; const float* b5  = (const float*)d_in[18];
    const float* w6  = (const float*)d_in[19]; const float* b6  = (const float*)d_in[20];
    const float* w7  = (const float*)d_in[21]; const float* b7  = (const float*)d_in[22];
    const float* w8  = (const float*)d_in[23]; const float* b8  = (const float*)d_in[24];
    const float* w9  = (const float*)d_in[25]; const float* b9  = (const float*)d_in[26];

    float* ws    = (float*)d_ws;
    float* ebuf  = ws;                   // 3*31*256    = 23808
    float* tA    = ebuf + 23808;         // 2*64*15*256 = 491520
    float* tB    = tA + 491520;          // 2*64*15*256 = 491520
    float* p0    = tB + 491520;          // 64*9*256    = 147456
    float* p1    = p0 + 147456;          // 64*9*256    = 147456
    float* preds = p1 + 147456;          // 16*3*256    = 12288

    hipMemcpyAsync(ebuf, x, 23808 * sizeof(float), hipMemcpyDeviceToDevice, stream);

    for (int i = 0; i < 16; ++i) {
        conv3Q<<<dim3(1, 15, 8), 256, 0, stream>>>(ebuf, i, w1x, b1x, w1e, b1e, tA);
        convQ<13, 15, 2><<<dim3(1, 13, 32), 256, 0, stream>>>(tA, w2x, b2x, w2e, b2e, tB);
        convQ<11, 13, 2><<<dim3(1, 11, 32), 256, 0, stream>>>(tB, w3x, b3x, w3e, b3e, tA);
        convQ<9, 11, 2><<<dim3(1, 9, 32), 256, 0, stream>>>(tA, w4x, b4x, w4e, b4e, tB);
        mm88<<<dim3(9, 8), 256, 0, stream>>>(tB, p0);
        convQ<7, 9, 1><<<dim3(1, 7, 16), 256, 0, stream>>>(p0, w5, b5, w5, b5, p1);
        convQ<5, 7, 1><<<dim3(1, 5, 16), 256, 0, stream>>>(p1, w6, b6, w6, b6, p0);
        convQ<3, 5, 1><<<dim3(1, 3, 16), 256, 0, stream>>>(p0, w7, b7, w7, b7, p1);
        convQ<1, 3, 1><<<dim3(1, 1, 16), 256, 0, stream>>>(p1, w8, b8, w8, b8, p0);
        conv9up<<<dim3(1, 1, 1), dim3(256, 4), 0, stream>>>(p0, w9, b9, x, ebuf, preds, i);
    }

    finalize<<<96, 256, 0, stream>>>(preds, ebuf, (float*)d_out);
}

// Round 12
// 1918.696 us; speedup vs baseline: 8.9994x; 1.3224x over previous
//
#include <hip/hip_runtime.h>

#define LEAKY(v) ((v) >= 0.f ? (v) : 0.01f * (v))

// ---------------- L1: CIN=3, PH=1 (slice-local), dual tower, quad-col ----------------
// grid (1, 15, 8): z=bz>>2, cq=bz&3. block 256 = 4 waves; wave wv -> couts cq*16+wv*4 ..+3.
__global__ __launch_bounds__(256, 2) void conv3Q(
    const float* __restrict__ ebuf, int i0,
    const float* __restrict__ w0, const float* __restrict__ b0,
    const float* __restrict__ w1, const float* __restrict__ b1,
    float* __restrict__ out)
{
    const int lane = threadIdx.x & 63;
    const int wv   = threadIdx.x >> 6;
    const int h  = blockIdx.y;             // 0..14
    const int cq = blockIdx.z & 3;
    const int z  = blockIdx.z >> 2;
    const int cout0 = __builtin_amdgcn_readfirstlane(cq * 16 + wv * 4);
    const float* W  = (z ? w1 : w0) + cout0 * 27;
    const float* Bv = z ? b1 : b0;

    float a[4][4] = {};
    #pragma unroll
    for (int kh = 0; kh < 3; ++kh) {
        const int r = h - 1 + kh;
        const bool valid = (r >= 0 && r < 15);          // pad within 15-row slice
        const float msk = valid ? 1.f : 0.f;
        #pragma unroll
        for (int c = 0; c < 3; ++c) {
            const float* rr = ebuf + c * (31 * 256) + (i0 + (valid ? r : 0)) * 256 + lane * 4;
            float4 v = *(const float4*)rr;
            v.x *= msk; v.y *= msk; v.z *= msk; v.w *= msk;
            float wl = __shfl_up(v.w, 1);   if (lane == 0)  wl = 0.f;
            float wr = __shfl_down(v.x, 1); if (lane == 63) wr = 0.f;
            const float win[6] = {wl, v.x, v.y, v.z, v.w, wr};
            #pragma unroll
            for (int j = 0; j < 4; ++j) {
                const float* wj = W + j * 27 + c * 9 + kh * 3;
                #pragma unroll
                for (int cc = 0; cc < 4; ++cc)
                    a[j][cc] += wj[0] * win[cc] + wj[1] * win[cc + 1] + wj[2] * win[cc + 2];
            }
        }
    }
    float* o = out + (size_t)z * 245760 + h * 256 + lane * 4;
    #pragma unroll
    for (int j = 0; j < 4; ++j) {
        const float bb = Bv[cout0 + j];
        float4 r4;
        r4.x = LEAKY(a[j][0] + bb);
        r4.y = LEAKY(a[j][1] + bb);
        r4.z = LEAKY(a[j][2] + bb);
        r4.w = LEAKY(a[j][3] + bb);
        *(float4*)(o + (cout0 + j) * (15 * 256)) = r4;
    }
}

// ---------------- CIN=64 conv: cin split over 4 waves, quad-col + shuffle ----------------
// grid (1, HOUT, NZ*64), block (64,4). Block = one (tower, cout, row).
// Wave y handles cins y*16..y*16+15 (4 unroll-groups deep chain); LDS reduce.
template<int HOUT, int INH, int NZ>
__global__ __launch_bounds__(256, 2) void convYQ(
    const float* __restrict__ in,
    const float* __restrict__ w0, const float* __restrict__ b0,
    const float* __restrict__ w1, const float* __restrict__ b1,
    float* __restrict__ out)
{
    const int lane = threadIdx.x;              // 0..63, col quad 4*lane..4*lane+3
    const int y    = threadIdx.y;              // 0..3 cin slice
    const int h  = blockIdx.y;
    const int gz = blockIdx.z;
    const int z    = (NZ == 2) ? (gz >> 6) : 0;
    const int cout = (NZ == 2) ? (gz & 63) : gz;
    const float* W  = (z ? w1 : w0) + cout * 576 + y * 16 * 9;
    const float* Bv = z ? b1 : b0;
    const float* ib = in + (size_t)z * (64 * INH * 256)
                         + y * 16 * (INH * 256) + h * 256 + lane * 4;

    float acc[4] = {};

    #pragma unroll 4
    for (int c = 0; c < 16; ++c) {
        const float* r_ = ib + c * (INH * 256);
        #pragma unroll
        for (int kh = 0; kh < 3; ++kh) {
            float4 v = *(const float4*)(r_ + kh * 256);
            float wl = __shfl_up(v.w, 1);   if (lane == 0)  wl = 0.f;
            float wr = __shfl_down(v.x, 1); if (lane == 63) wr = 0.f;
            const float win[6] = {wl, v.x, v.y, v.z, v.w, wr};
            const float* wj = W + c * 9 + kh * 3;
            #pragma unroll
            for (int cc = 0; cc < 4; ++cc)
                acc[cc] += wj[0] * win[cc] + wj[1] * win[cc + 1] + wj[2] * win[cc + 2];
        }
    }

    __shared__ float red[4][256];
    *(float4*)&red[y][lane * 4] = *(float4*)acc;
    __syncthreads();

    // thread (lane,y) finalizes col y*64+lane: conflict-free reads, coalesced store
    const int col = y * 64 + lane;
    float v = Bv[cout] + red[0][col] + red[1][col] + red[2][col] + red[3][col];
    float* o = out + (size_t)z * (64 * HOUT * 256) + cout * (HOUT * 256) + h * 256;
    o[col] = LEAKY(v);
}

// ---------------- Per-pixel 8x8 @ 8x8 (fp32) ----------------
// grid (9, 8), block 256. Towers in tB at stride 64*9*256.
__global__ __launch_bounds__(256, 2) void mm88(const float* __restrict__ tw,
                                               float* __restrict__ p0)
{
    const int idx = blockIdx.x * 256 + threadIdx.x;   // pixel in 9*256
    const int i   = blockIdx.y;                       // 0..7
    const float* s = tw;                              // tower 0 (x-weights / s)
    const float* e = tw + 64 * 9 * 256;               // tower 1 (e)
    float sv[64];
    #pragma unroll
    for (int c = 0; c < 64; ++c) sv[c] = s[c * (9 * 256) + idx];
    float ev[8];
    #pragma unroll
    for (int j = 0; j < 8; ++j) ev[j] = e[(i * 8 + j) * (9 * 256) + idx];
    #pragma unroll
    for (int k = 0; k < 8; ++k) {
        float acc = 0.f;
        #pragma unroll
        for (int j = 0; j < 8; ++j) acc += ev[j] * sv[j * 8 + k];
        p0[(i * 8 + k) * (9 * 256) + idx] = acc;
    }
}

// ---------------- conv9 (64->3, kh=1 taps only) + recurrence update ----------------
// block (256,4): threadIdx.y owns 16 cins; LDS reduce; y==0 finalizes.
__global__ void conv9up(const float* __restrict__ pin, const float* __restrict__ w9,
                        const float* __restrict__ b9, const float* __restrict__ x,
                        float* __restrict__ ebuf, float* __restrict__ preds, int i)
{
    const int wcol = threadIdx.x;
    const int yq   = threadIdx.y;       // 0..3
    const int c0   = yq * 16;
    const bool mL = (wcol > 0), mR = (wcol < 255);
    float a0 = 0.f, a1 = 0.f, a2 = 0.f;

    #pragma unroll 4
    for (int c = 0; c < 16; ++c) {
        const int cin = c0 + c;
        const float* r_ = pin + cin * 256;
        float vm = mL ? r_[wcol - 1] : 0.f;
        float v0 = r_[wcol];
        float vp = mR ? r_[wcol + 1] : 0.f;
        const float* wk0 = w9 + (0 * 64 + cin) * 9 + 3;   // kh=1
        const float* wk1 = w9 + (1 * 64 + cin) * 9 + 3;
        const float* wk2 = w9 + (2 * 64 + cin) * 9 + 3;
        a0 += vm * wk0[0] + v0 * wk0[1] + vp * wk0[2];
        a1 += vm * wk1[0] + v0 * wk1[1] + vp * wk1[2];
        a2 += vm * wk2[0] + v0 * wk2[1] + vp * wk2[2];
    }

    __shared__ float red[4][3][256];
    red[yq][0][wcol] = a0;
    red[yq][1][wcol] = a1;
    red[yq][2][wcol] = a2;
    __syncthreads();

    if (yq == 0) {
        #pragma unroll
        for (int j = 0; j < 3; ++j) {
            float v = b9[j] + red[0][j][wcol] + red[1][j][wcol]
                            + red[2][j][wcol] + red[3][j][wcol];
            v = LEAKY(v);
            preds[i * 768 + j * 256 + wcol] = v;
            ebuf[j * 31 * 256 + (15 + i) * 256 + wcol] =
                x[j * 31 * 256 + (15 + i) * 256 + wcol] - v;
        }
    }
}

// ---------------- finalize ----------------
__global__ void finalize(const float* __restrict__ preds, const float* __restrict__ ebuf,
                         float* __restrict__ o)
{
    const int idx = blockIdx.x * 256 + threadIdx.x;
    if (idx >= 24576) return;
    if (idx < 12288) {
        const int c = idx >> 12;
        const int t = (idx >> 8) & 15;
        const int w = idx & 255;
        o[idx] = preds[t * 768 + c * 256 + w];
    } else {
        const int j = idx - 12288;
        const int c = j >> 12;
        const int t = (j >> 8) & 15;
        const int w = j & 255;
        o[idx] = ebuf[c * 31 * 256 + (15 + t) * 256 + w];
    }
}

extern "C" void kernel_launch(void* const* d_in, const int* in_sizes, int n_in,
                              void* d_out, int out_size, void* d_ws, size_t ws_size,
                              hipStream_t stream)
{
    const float* x   = (const float*)d_in[0];
    const float* w1x = (const float*)d_in[1];  const float* b1x = (const float*)d_in[2];
    const float* w2x = (const float*)d_in[3];  const float* b2x = (const float*)d_in[4];
    const float* w3x = (const float*)d_in[5];  const float* b3x = (const float*)d_in[6];
    const float* w4x = (const float*)d_in[7];  const float* b4x = (const float*)d_in[8];
    const float* w1e = (const float*)d_in[9];  const float* b1e = (const float*)d_in[10];
    const float* w2e = (const float*)d_in[11]; const float* b2e = (const float*)d_in[12];
    const float* w3e = (const float*)d_in[13]; const float* b3e = (const float*)d_in[14];
    const float* w4e = (const float*)d_in[15]; const float* b4e = (const float*)d_in[16];
    const float* w5  = (const float*)d_in[17]; const float* b5  = (const float*)d_in[18];
    const float* w6  = (const float*)d_in[19]; const float* b6  = (const float*)d_in[20];
    const float* w7  = (const float*)d_in[21]; const float* b7  = (const float*)d_in[22];
    const float* w8  = (const float*)d_in[23]; const float* b8  = (const float*)d_in[24];
    const float* w9  = (const float*)d_in[25]; const float* b9  = (const float*)d_in[26];

    float* ws    = (float*)d_ws;
    float* ebuf  = ws;                   // 3*31*256    = 23808
    float* tA    = ebuf + 23808;         // 2*64*15*256 = 491520
    float* tB    = tA + 491520;          // 2*64*15*256 = 491520
    float* p0    = tB + 491520;          // 64*9*256    = 147456
    float* p1    = p0 + 147456;          // 64*9*256    = 147456
    float* preds = p1 + 147456;          // 16*3*256    = 12288

    hipMemcpyAsync(ebuf, x, 23808 * sizeof(float), hipMemcpyDeviceToDevice, stream);

    const dim3 cb(64, 4);
    for (int i = 0; i < 16; ++i) {
        conv3Q<<<dim3(1, 15, 8), 256, 0, stream>>>(ebuf, i, w1x, b1x, w1e, b1e, tA);
        convYQ<13, 15, 2><<<dim3(1, 13, 128), cb, 0, stream>>>(tA, w2x, b2x, w2e, b2e, tB);
        convYQ<11, 13, 2><<<dim3(1, 11, 128), cb, 0, stream>>>(tB, w3x, b3x, w3e, b3e, tA);
        convYQ<9, 11, 2><<<dim3(1, 9, 128), cb, 0, stream>>>(tA, w4x, b4x, w4e, b4e, tB);
        mm88<<<dim3(9, 8), 256, 0, stream>>>(tB, p0);
        convYQ<7, 9, 1><<<dim3(1, 7, 64), cb, 0, stream>>>(p0, w5, b5, w5, b5, p1);
        convYQ<5, 7, 1><<<dim3(1, 5, 64), cb, 0, stream>>>(p1, w6, b6, w6, b6, p0);
        convYQ<3, 5, 1><<<dim3(1, 3, 64), cb, 0, stream>>>(p0, w7, b7, w7, b7, p1);
        convYQ<1, 3, 1><<<dim3(1, 1, 64), cb, 0, stream>>>(p1, w8, b8, w8, b8, p0);
        conv9up<<<dim3(1, 1, 1), dim3(256, 4), 0, stream>>>(p0, w9, b9, x, ebuf, preds, i);
    }

    finalize<<<96, 256, 0, stream>>>(preds, ebuf, (float*)d_out);
}

// Round 14
// 1905.487 us; speedup vs baseline: 9.0618x; 1.0069x over previous
//
#include <hip/hip_runtime.h>

#define LEAKY(v) ((v) >= 0.f ? (v) : 0.01f * (v))

#define CS   4608      // ring channel stride in floats (18 rows * 256)
#define ZS1  294912    // ring tower stride (64 * CS)
#define TSL  16        // T (top-pad) slot
#define BSL  17        // B (bottom-pad) slot
#define EBCS 7936      // ebuf channel stride (31*256)

// ---------------- generic incremental CIN=64 conv: up to 6 (job,tower) units ----------------
// grid: NU*64 blocks of (64,4). Unit q = bx>>6, cout = bx&63. Wave y handles cins y*16..+15.
struct JobD { const float* t0; const float* t1; const float* t2; float* o; };
struct IncP { JobD jd[6]; };

__global__ __launch_bounds__(256, 2) void convInc(
    IncP P, const float* __restrict__ W0, const float* __restrict__ B0,
    const float* __restrict__ W1, const float* __restrict__ B1,
    int zsel, int ics, int ocs)
{
    const int lane = threadIdx.x;          // 0..63 (col quad)
    const int y    = threadIdx.y;          // 0..3  (cin slice)
    const int q    = blockIdx.x >> 6;
    const int cout = blockIdx.x & 63;
    const int z    = (zsel >> q) & 1;
    const float* W  = (z ? W1 : W0) + cout * 576 + y * 144;
    const float* Bv = z ? B1 : B0;
    const JobD jd  = P.jd[q];
    const int yo   = y * 16 * ics + lane * 4;
    const float* t0 = jd.t0 + yo;
    const float* t1 = jd.t1 + yo;
    const float* t2 = jd.t2 + yo;

    float acc[4] = {};
    #pragma unroll 4
    for (int c = 0; c < 16; ++c) {
        #pragma unroll
        for (int t = 0; t < 3; ++t) {
            const float* rp = (t == 0 ? t0 : (t == 1 ? t1 : t2)) + c * ics;
            float4 v = *(const float4*)rp;
            float wl = __shfl_up(v.w, 1);   if (lane == 0)  wl = 0.f;
            float wr = __shfl_down(v.x, 1); if (lane == 63) wr = 0.f;
            const float win[6] = {wl, v.x, v.y, v.z, v.w, wr};
            const float* wj = W + c * 9 + t * 3;
            #pragma unroll
            for (int cc = 0; cc < 4; ++cc)
                acc[cc] += wj[0] * win[cc] + wj[1] * win[cc + 1] + wj[2] * win[cc + 2];
        }
    }

    __shared__ float red[4][256];
    *(float4*)&red[y][lane * 4] = *(float4*)acc;
    __syncthreads();
    const int col = y * 64 + lane;
    float v = Bv[cout] + red[0][col] + red[1][col] + red[2][col] + red[3][col];
    jd.o[cout * ocs + col] = LEAKY(v);
}

// ---------------- incremental L1 (CIN=3 from ebuf): 3 jobs x 2 towers ----------------
// grid 24 = job*8 + z*4 + cq; block 256 (4 waves x 4 couts). Null tap = zero row.
struct C3P { const float* t[3][3]; float* o[3][2]; };

__global__ __launch_bounds__(256, 2) void conv3inc(
    C3P P, const float* __restrict__ W0, const float* __restrict__ B0,
    const float* __restrict__ W1, const float* __restrict__ B1)
{
    const int lane = threadIdx.x & 63;
    const int wv   = threadIdx.x >> 6;
    const int job  = blockIdx.x >> 3;
    const int cq   = blockIdx.x & 3;
    const int z    = (blockIdx.x >> 2) & 1;
    const int cout0 = __builtin_amdgcn_readfirstlane(cq * 16 + wv * 4);
    const float* W  = (z ? W1 : W0) + cout0 * 27;
    const float* Bv = z ? B1 : B0;

    float a[4][4] = {};
    #pragma unroll
    for (int t = 0; t < 3; ++t) {
        const float* rp = P.t[job][t];
        if (rp) {
            #pragma unroll
            for (int c = 0; c < 3; ++c) {
                float4 v = *(const float4*)(rp + c * EBCS + lane * 4);
                float wl = __shfl_up(v.w, 1);   if (lane == 0)  wl = 0.f;
                float wr = __shfl_down(v.x, 1); if (lane == 63) wr = 0.f;
                const float win[6] = {wl, v.x, v.y, v.z, v.w, wr};
                #pragma unroll
                for (int j = 0; j < 4; ++j) {
                    const float* wj = W + j * 27 + c * 9 + t * 3;
                    #pragma unroll
                    for (int cc = 0; cc < 4; ++cc)
                        a[j][cc] += wj[0] * win[cc] + wj[1] * win[cc + 1] + wj[2] * win[cc + 2];
                }
            }
        }
    }
    float* o = P.o[job][z];
    #pragma unroll
    for (int j = 0; j < 4; ++j) {
        const float bb = Bv[cout0 + j];
        float4 r4;
        r4.x = LEAKY(a[j][0] + bb); r4.y = LEAKY(a[j][1] + bb);
        r4.z = LEAKY(a[j][2] + bb); r4.w = LEAKY(a[j][3] + bb);
        *(float4*)(o + (cout0 + j) * CS + lane * 4) = r4;
    }
}

// ---------------- bootstrap L1 (i=0, full 15 rows) into ring layout ----------------
__global__ __launch_bounds__(256, 2) void conv3B(
    const float* __restrict__ ebuf,
    const float* __restrict__ W0, const float* __restrict__ B0,
    const float* __restrict__ W1, const float* __restrict__ B1,
    float* __restrict__ out)
{
    const int lane = threadIdx.x & 63;
    const int wv   = threadIdx.x >> 6;
    const int h  = blockIdx.y;             // 0..14
    const int cq = blockIdx.z & 3;
    const int z  = blockIdx.z >> 2;
    const int cout0 = __builtin_amdgcn_readfirstlane(cq * 16 + wv * 4);
    const float* W  = (z ? W1 : W0) + cout0 * 27;
    const float* Bv = z ? B1 : B0;

    float a[4][4] = {};
    #pragma unroll
    for (int kh = 0; kh < 3; ++kh) {
        const int r = h - 1 + kh;
        const bool valid = (r >= 0 && r < 15);
        const float msk = valid ? 1.f : 0.f;
        #pragma unroll
        for (int c = 0; c < 3; ++c) {
            const float* rr = ebuf + c * EBCS + (valid ? r : 0) * 256 + lane * 4;
            float4 v = *(const float4*)rr;
            v.x *= msk; v.y *= msk; v.z *= msk; v.w *= msk;
            float wl = __shfl_up(v.w, 1);   if (lane == 0)  wl = 0.f;
            float wr = __shfl_down(v.x, 1); if (lane == 63) wr = 0.f;
            const float win[6] = {wl, v.x, v.y, v.z, v.w, wr};
            #pragma unroll
            for (int j = 0; j < 4; ++j) {
                const float* wj = W + j * 27 + c * 9 + kh * 3;
                #pragma unroll
                for (int cc = 0; cc < 4; ++cc)
                    a[j][cc] += wj[0] * win[cc] + wj[1] * win[cc + 1] + wj[2] * win[cc + 2];
            }
        }
    }
    const int slot = (h == 0) ? TSL : (h == 14 ? BSL : (h & 15));
    float* o = out + (size_t)z * ZS1 + slot * 256;
    #pragma unroll
    for (int j = 0; j < 4; ++j) {
        const float bb = Bv[cout0 + j];
        float4 r4;
        r4.x = LEAKY(a[j][0] + bb); r4.y = LEAKY(a[j][1] + bb);
        r4.z = LEAKY(a[j][2] + bb); r4.w = LEAKY(a[j][3] + bb);
        *(float4*)(o + (cout0 + j) * CS + lane * 4) = r4;
    }
}

// ---------------- bootstrap CIN=64 conv (i=0, full height) ring->ring ----------------
template<int HOUT, int HIN, int OFFI, int OFFO, int NZ>
__global__ __launch_bounds__(256, 2) void convYB(
    const float* __restrict__ in,
    const float* __restrict__ W0, const float* __restrict__ B0,
    const float* __restrict__ W1, const float* __restrict__ B1,
    float* __restrict__ out)
{
    const int lane = threadIdx.x;
    const int y    = threadIdx.y;
    const int h  = blockIdx.y;
    const int gz = blockIdx.z;
    const int z    = (NZ == 2) ? (gz >> 6) : 0;
    const int cout = (NZ == 2) ? (gz & 63) : gz;
    const float* W  = (z ? W1 : W0) + cout * 576 + y * 144;
    const float* Bv = z ? B1 : B0;
    const float* ib = in + (size_t)z * ZS1 + y * 16 * CS + lane * 4;

    int slot[3];
    #pragma unroll
    for (int t = 0; t < 3; ++t) {
        const int g = h + t;
        slot[t] = (g == 0) ? TSL : (g == HIN - 1 ? BSL : ((g + OFFI) & 15));
    }

    float acc[4] = {};
    #pragma unroll 4
    for (int c = 0; c < 16; ++c) {
        #pragma unroll
        for (int t = 0; t < 3; ++t) {
            float4 v = *(const float4*)(ib + c * CS + slot[t] * 256);
            float wl = __shfl_up(v.w, 1);   if (lane == 0)  wl = 0.f;
            float wr = __shfl_down(v.x, 1); if (lane == 63) wr = 0.f;
            const float win[6] = {wl, v.x, v.y, v.z, v.w, wr};
            const float* wj = W + c * 9 + t * 3;
            #pragma unroll
            for (int cc = 0; cc < 4; ++cc)
                acc[cc] += wj[0] * win[cc] + wj[1] * win[cc + 1] + wj[2] * win[cc + 2];
        }
    }

    __shared__ float red[4][256];
    *(float4*)&red[y][lane * 4] = *(float4*)acc;
    __syncthreads();
    const int col = y * 64 + lane;
    const int os = (h == 0) ? TSL : (h == HOUT - 1 ? BSL : ((h + OFFO) & 15));
    float v = Bv[cout] + red[0][col] + red[1][col] + red[2][col] + red[3][col];
    out[(size_t)z * ZS1 + cout * CS + os * 256 + col] = LEAKY(v);
}

// ---------------- bootstrap mm (9 rows) ----------------
__global__ __launch_bounds__(256, 2) void mmB(const float* __restrict__ L4R,
                                              float* __restrict__ MMR)
{
    const int col = threadIdx.x;
    const int r   = blockIdx.x;            // 0..8
    const int ig  = blockIdx.y;            // 0..7
    const int slot = (r == 0) ? TSL : (r == 8 ? BSL : ((r + 3) & 15));
    const float* s = L4R + slot * 256 + col;
    const float* e = L4R + ZS1 + slot * 256 + col;
    float sv[64];
    #pragma unroll
    for (int c = 0; c < 64; ++c) sv[c] = s[c * CS];
    float ev[8];
    #pragma unroll
    for (int j = 0; j < 8; ++j) ev[j] = e[(ig * 8 + j) * CS];
    #pragma unroll
    for (int k = 0; k < 8; ++k) {
        float acc = 0.f;
        #pragma unroll
        for (int j = 0; j < 8; ++j) acc += ev[j] * sv[j * 8 + k];
        MMR[(ig * 8 + k) * CS + slot * 256 + col] = acc;
    }
}

// ---------------- incremental mm: 3 jobs (T, B, new-full) ----------------
struct MMP { const float* s[3]; const float* e[3]; float* o[3]; };
__global__ __launch_bounds__(256, 2) void mminc(MMP P)
{
    const int col = threadIdx.x;
    const int job = blockIdx.x;            // 0..2
    const int ig  = blockIdx.y;            // 0..7
    const float* s = P.s[job] + col;
    const float* e = P.e[job] + col;
    float sv[64];
    #pragma unroll
    for (int c = 0; c < 64; ++c) sv[c] = s[c * CS];
    float ev[8];
    #pragma unroll
    for (int j = 0; j < 8; ++j) ev[j] = e[(ig * 8 + j) * CS];
    float* o = P.o[job];
    #pragma unroll
    for (int k = 0; k < 8; ++k) {
        float acc = 0.f;
        #pragma unroll
        for (int j = 0; j < 8; ++j) acc += ev[j] * sv[j * 8 + k];
        o[(ig * 8 + k) * CS + col] = acc;
    }
}

// ---------------- conv9 (64->3, kh=1 taps only) + recurrence update ----------------
__global__ void conv9up(const float* __restrict__ pin, const float* __restrict__ w9,
                        const float* __restrict__ b9, const float* __restrict__ x,
                        float* __restrict__ ebuf, float* __restrict__ preds, int i)
{
    const int wcol = threadIdx.x;
    const int yq   = threadIdx.y;
    const int c0   = yq * 16;
    const bool mL = (wcol > 0), mR = (wcol < 255);
    float a0 = 0.f, a1 = 0.f, a2 = 0.f;

    #pragma unroll 4
    for (int c = 0; c < 16; ++c) {
        const int cin = c0 + c;
        const float* r_ = pin + cin * 256;
        float vm = mL ? r_[wcol - 1] : 0.f;
        float v0 = r_[wcol];
        float vp = mR ? r_[wcol + 1] : 0.f;
        const float* wk0 = w9 + (0 * 64 + cin) * 9 + 3;
        const float* wk1 = w9 + (1 * 64 + cin) * 9 + 3;
        const float* wk2 = w9 + (2 * 64 + cin) * 9 + 3;
        a0 += vm * wk0[0] + v0 * wk0[1] + vp * wk0[2];
        a1 += vm * wk1[0] + v0 * wk1[1] + vp * wk1[2];
        a2 += vm * wk2[0] + v0 * wk2[1] + vp * wk2[2];
    }

    __shared__ float red[4][3][256];
    red[yq][0][wcol] = a0;
    red[yq][1][wcol] = a1;
    red[yq][2][wcol] = a2;
    __syncthreads();

    if (yq == 0) {
        #pragma unroll
        for (int j = 0; j < 3; ++j) {
            float v = b9[j] + red[0][j][wcol] + red[1][j][wcol]
                            + red[2][j][wcol] + red[3][j][wcol];
            v = LEAKY(v);
            preds[i * 768 + j * 256 + wcol] = v;
            ebuf[j * EBCS + (15 + i) * 256 + wcol] =
                x[j * EBCS + (15 + i) * 256 + wcol] - v;
        }
    }
}

// ---------------- finalize ----------------
__global__ void finalize(const float* __restrict__ preds, const float* __restrict__ ebuf,
                         float* __restrict__ o)
{
    const int idx = blockIdx.x * 256 + threadIdx.x;
    if (idx >= 24576) return;
    if (idx < 12288) {
        const int c = idx >> 12;
        const int t = (idx >> 8) & 15;
        const int w = idx & 255;
        o[idx] = preds[t * 768 + c * 256 + w];
    } else {
        const int j = idx - 12288;
        const int c = j >> 12;
        const int t = (j >> 8) & 15;
        const int w = j & 255;
        o[idx] = ebuf[c * EBCS + (15 + t) * 256 + w];
    }
}

extern "C" void kernel_launch(void* const* d_in, const int* in_sizes, int n_in,
                              void* d_out, int out_size, void* d_ws, size_t ws_size,
                              hipStream_t stream)
{
    const float* x   = (const float*)d_in[0];
    const float* w1x = (const float*)d_in[1];  const float* b1x = (const float*)d_in[2];
    const float* w2x = (const float*)d_in[3];  const float* b2x = (const float*)d_in[4];
    const float* w3x = (const float*)d_in[5];  const float* b3x = (const float*)d_in[6];
    const float* w4x = (const float*)d_in[7];  const float* b4x = (const float*)d_in[8];
    const float* w1e = (const float*)d_in[9];  const float* b1e = (const float*)d_in[10];
    const float* w2e = (const float*)d_in[11]; const float* b2e = (const float*)d_in[12];
    const float* w3e = (const float*)d_in[13]; const float* b3e = (const float*)d_in[14];
    const float* w4e = (const float*)d_in[15]; const float* b4e = (const float*)d_in[16];
    const float* w5  = (const float*)d_in[17]; const float* b5  = (const float*)d_in[18];
    const float* w6  = (const float*)d_in[19]; const float* b6  = (const float*)d_in[20];
    const float* w7  = (const float*)d_in[21]; const float* b7  = (const float*)d_in[22];
    const float* w8  = (const float*)d_in[23]; const float* b8  = (const float*)d_in[24];
    const float* w9  = (const float*)d_in[25]; const float* b9  = (const float*)d_in[26];

    float* ws    = (float*)d_ws;
    float* ebuf  = ws;                    // 23808
    float* L1R   = ebuf + 23808;          // 2*ZS1 = 589824
    float* L2R   = L1R + 589824;
    float* L3R   = L2R + 589824;
    float* L4R   = L3R + 589824;
    float* MMR   = L4R + 589824;          // 294912
    float* L5R   = MMR + 294912;
    float* L6R   = L5R + 294912;
    float* L7b   = L6R + 294912;          // 64*768 = 49152
    float* L8b   = L7b + 49152;           // 16384
    float* preds = L8b + 16384;           // 12288

    auto S2 = [](int c) { return c & 15; };
    auto r2 = [](float* b, int z, int slot) { return b + (size_t)z * ZS1 + slot * 256; };
    auto r1 = [](float* b, int slot) { return b + slot * 256; };

    hipMemcpyAsync(ebuf, x, 23808 * sizeof(float), hipMemcpyDeviceToDevice, stream);

    const dim3 cb(64, 4);

    // ---- bootstrap (step 0) ----
    conv3B<<<dim3(1, 15, 8), 256, 0, stream>>>(ebuf, w1x, b1x, w1e, b1e, L1R);
    convYB<13, 15, 0, 1, 2><<<dim3(1, 13, 128), cb, 0, stream>>>(L1R, w2x, b2x, w2e, b2e, L2R);
    convYB<11, 13, 1, 2, 2><<<dim3(1, 11, 128), cb, 0, stream>>>(L2R, w3x, b3x, w3e, b3e, L3R);
    convYB<9, 11, 2, 3, 2><<<dim3(1, 9, 128), cb, 0, stream>>>(L3R, w4x, b4x, w4e, b4e, L4R);
    mmB<<<dim3(9, 8), 256, 0, stream>>>(L4R, MMR);
    convYB<7, 9, 3, 4, 1><<<dim3(1, 7, 64), cb, 0, stream>>>(MMR, w5, b5, w5, b5, L5R);
    convYB<5, 7, 4, 5, 1><<<dim3(1, 5, 64), cb, 0, stream>>>(L5R, w6, b6, w6, b6, L6R);

    for (int i = 0; i < 16; ++i) {
        if (i > 0) {
            // L1 fresh: T1, B1, L1full[i+13]
            C3P p3 = {};
            p3.t[0][0] = nullptr;                p3.t[0][1] = ebuf + i * 256;        p3.t[0][2] = ebuf + (i + 1) * 256;
            p3.t[1][0] = ebuf + (i + 13) * 256;  p3.t[1][1] = ebuf + (i + 14) * 256; p3.t[1][2] = nullptr;
            p3.t[2][0] = ebuf + (i + 12) * 256;  p3.t[2][1] = ebuf + (i + 13) * 256; p3.t[2][2] = ebuf + (i + 14) * 256;
            for (int z = 0; z < 2; ++z) {
                p3.o[0][z] = r2(L1R, z, TSL);
                p3.o[1][z] = r2(L1R, z, BSL);
                p3.o[2][z] = r2(L1R, z, S2(i + 13));
            }
            conv3inc<<<24, 256, 0, stream>>>(p3, w1x, b1x, w1e, b1e);

            // L2 fresh
            IncP p2 = {};
            for (int z = 0; z < 2; ++z) {
                p2.jd[0 * 2 + z] = { r2(L1R, z, TSL),        r2(L1R, z, S2(i + 1)),  r2(L1R, z, S2(i + 2)),  r2(L2R, z, TSL) };
                p2.jd[1 * 2 + z] = { r2(L1R, z, S2(i + 12)), r2(L1R, z, S2(i + 13)), r2(L1R, z, BSL),        r2(L2R, z, BSL) };
                p2.jd[2 * 2 + z] = { r2(L1R, z, S2(i + 11)), r2(L1R, z, S2(i + 12)), r2(L1R, z, S2(i + 13)), r2(L2R, z, S2(i + 12)) };
            }
            convInc<<<384, cb, 0, stream>>>(p2, w2x, b2x, w2e, b2e, 42, CS, CS);

            // L3 fresh
            IncP p3i = {};
            for (int z = 0; z < 2; ++z) {
                p3i.jd[0 * 2 + z] = { r2(L2R, z, TSL),        r2(L2R, z, S2(i + 2)),  r2(L2R, z, S2(i + 3)),  r2(L3R, z, TSL) };
                p3i.jd[1 * 2 + z] = { r2(L2R, z, S2(i + 11)), r2(L2R, z, S2(i + 12)), r2(L2R, z, BSL),        r2(L3R, z, BSL) };
                p3i.jd[2 * 2 + z] = { r2(L2R, z, S2(i + 10)), r2(L2R, z, S2(i + 11)), r2(L2R, z, S2(i + 12)), r2(L3R, z, S2(i + 11)) };
            }
            convInc<<<384, cb, 0, stream>>>(p3i, w3x, b3x, w3e, b3e, 42, CS, CS);

            // L4 fresh
            IncP p4 = {};
            for (int z = 0; z < 2; ++z) {
                p4.jd[0 * 2 + z] = { r2(L3R, z, TSL),        r2(L3R, z, S2(i + 3)),  r2(L3R, z, S2(i + 4)),  r2(L4R, z, TSL) };
                p4.jd[1 * 2 + z] = { r2(L3R, z, S2(i + 10)), r2(L3R, z, S2(i + 11)), r2(L3R, z, BSL),        r2(L4R, z, BSL) };
                p4.jd[2 * 2 + z] = { r2(L3R, z, S2(i + 9)),  r2(L3R, z, S2(i + 10)), r2(L3R, z, S2(i + 11)), r2(L4R, z, S2(i + 10)) };
            }
            convInc<<<384, cb, 0, stream>>>(p4, w4x, b4x, w4e, b4e, 42, CS, CS);

            // mm fresh
            MMP pm;
            pm.s[0] = r2(L4R, 0, TSL);        pm.e[0] = r2(L4R, 1, TSL);        pm.o[0] = r1(MMR, TSL);
            pm.s[1] = r2(L4R, 0, BSL);        pm.e[1] = r2(L4R, 1, BSL);        pm.o[1] = r1(MMR, BSL);
            pm.s[2] = r2(L4R, 0, S2(i + 10)); pm.e[2] = r2(L4R, 1, S2(i + 10)); pm.o[2] = r1(MMR, S2(i + 10));
            mminc<<<dim3(3, 8), 256, 0, stream>>>(pm);

            // L5 fresh
            IncP p5 = {};
            p5.jd[0] = { r1(MMR, TSL),       r1(MMR, S2(i + 4)),  r1(MMR, S2(i + 5)),  r1(L5R, TSL) };
            p5.jd[1] = { r1(MMR, S2(i + 9)), r1(MMR, S2(i + 10)), r1(MMR, BSL),        r1(L5R, BSL) };
            p5.jd[2] = { r1(MMR, S2(i + 8)), r1(MMR, S2(i + 9)),  r1(MMR, S2(i + 10)), r1(L5R, S2(i + 9)) };
            convInc<<<192, cb, 0, stream>>>(p5, w5, b5, w5, b5, 0, CS, CS);

            // L6 fresh  [FIXED: T-job taps were off by one (S2(i+6),S2(i+7))]
            IncP p6 = {};
            p6.jd[0] = { r1(L5R, TSL),       r1(L5R, S2(i + 5)), r1(L5R, S2(i + 6)), r1(L6R, TSL) };
            p6.jd[1] = { r1(L5R, S2(i + 8)), r1(L5R, S2(i + 9)), r1(L5R, BSL),       r1(L6R, BSL) };
            p6.jd[2] = { r1(L5R, S2(i + 7)), r1(L5R, S2(i + 8)), r1(L5R, S2(i + 9)), r1(L6R, S2(i + 8)) };
            convInc<<<192, cb, 0, stream>>>(p6, w6, b6, w6, b6, 0, CS, CS);
        }

        // L7 (all 3 rows fresh every step)
        IncP p7 = {};
        p7.jd[0] = { r1(L6R, TSL),       r1(L6R, S2(i + 6)), r1(L6R, S2(i + 7)), L7b };
        p7.jd[1] = { r1(L6R, S2(i + 6)), r1(L6R, S2(i + 7)), r1(L6R, S2(i + 8)), L7b + 256 };
        p7.jd[2] = { r1(L6R, S2(i + 7)), r1(L6R, S2(i + 8)), r1(L6R, BSL),       L7b + 512 };
        convInc<<<192, cb, 0, stream>>>(p7, w7, b7, w7, b7, 0, CS, 768);

        // L8 (1 row)
        IncP p8 = {};
        p8.jd[0] = { L7b, L7b + 256, L7b + 512, L8b };
        convInc<<<64, cb, 0, stream>>>(p8, w8, b8, w8, b8, 0, 768, 256);

        conv9up<<<dim3(1, 1, 1), dim3(256, 4), 0, stream>>>(L8b, w9, b9, x, ebuf, preds, i);
    }

    finalize<<<96, 256, 0, stream>>>(preds, ebuf, (float*)d_out);
}